// Round 5
// baseline (577.578 us; speedup 1.0000x reference)
//
#include <hip/hip_runtime.h>
#include <math.h>

#define NN 50000
#define NE 800000

typedef float  f32x4  __attribute__((ext_vector_type(4)));
typedef __bf16 bf16x8 __attribute__((ext_vector_type(8)));

// ws layout: [0,256) m_agg_w (64 f32). [256,...) bf16 weight fragments,
// 16B chunks, fragment-linear (chunk = tile*64 + lane):
#define WE1F_OFF 0        // 5120: We1||Wg1  (kc<5, ct<16)  K 136->160
#define WE2F_OFF 5120     // 1024: We2       (kc<4, ct<4)
#define WN1F_OFF 6144     // 2048: Wn1       (kc<4, ct<8)
#define WN2F_OFF 8192     // 1024: Wn2       (kc<4, ct<4)
#define WW1F_OFF 9216     // 1536: Ww1       (kc<3, ct<8)   K 67->96
#define WW2F_OFF 10752    // 1024: Ww2       (kc<4, ct<4)
#define NCHUNKS  11776

__device__ inline bf16x8 pack8(float4 a, float4 b) {
    bf16x8 r;
    r[0] = (__bf16)a.x; r[1] = (__bf16)a.y; r[2] = (__bf16)a.z; r[3] = (__bf16)a.w;
    r[4] = (__bf16)b.x; r[5] = (__bf16)b.y; r[6] = (__bf16)b.z; r[7] = (__bf16)b.w;
    return r;
}

// ---------------- weight fragment pre-pack ----------------
__global__ __launch_bounds__(256) void pack_weights(
    const float* __restrict__ We1, const float* __restrict__ Wg1,
    const float* __restrict__ We2, const float* __restrict__ Wn1,
    const float* __restrict__ Wn2, const float* __restrict__ Ww1,
    const float* __restrict__ Ww2, bf16x8* __restrict__ wsF)
{
    int c = blockIdx.x * 256 + threadIdx.x;
    if (c >= NCHUNKS) return;
    const int lane = c & 63, l16 = lane & 15, row8 = ((lane >> 4) & 3) * 8;
    bf16x8 p;
    if (c < WE2F_OFF) {                       // We1 || Wg1, pad K 136->160
        int ct = (c >> 6) & 15, kc = c >> 10;
        int col = ct * 16 + l16;
        const float* src = (col < 128) ? (We1 + col) : (Wg1 + (col - 128));
#pragma unroll
        for (int i = 0; i < 8; i++) {
            int r = kc * 32 + row8 + i;
            p[i] = (__bf16)((r < 136) ? src[(size_t)r * 128] : 0.f);
        }
    } else if (c < WN1F_OFF) {
        int cc = c - WE2F_OFF; int ct = (cc >> 6) & 3, kc = cc >> 8;
        int col = ct * 16 + l16;
#pragma unroll
        for (int i = 0; i < 8; i++)
            p[i] = (__bf16)We2[(size_t)(kc * 32 + row8 + i) * 64 + col];
    } else if (c < WN2F_OFF) {
        int cc = c - WN1F_OFF; int ct = (cc >> 6) & 7, kc = cc >> 9;
        int col = ct * 16 + l16;
#pragma unroll
        for (int i = 0; i < 8; i++)
            p[i] = (__bf16)Wn1[(size_t)(kc * 32 + row8 + i) * 128 + col];
    } else if (c < WW1F_OFF) {
        int cc = c - WN2F_OFF; int ct = (cc >> 6) & 3, kc = cc >> 8;
        int col = ct * 16 + l16;
#pragma unroll
        for (int i = 0; i < 8; i++)
            p[i] = (__bf16)Wn2[(size_t)(kc * 32 + row8 + i) * 64 + col];
    } else if (c < WW2F_OFF) {                // Ww1, pad K 67->96
        int cc = c - WW1F_OFF; int ct = (cc >> 6) & 7, kc = cc >> 9;
        int col = ct * 16 + l16;
#pragma unroll
        for (int i = 0; i < 8; i++) {
            int r = kc * 32 + row8 + i;
            p[i] = (__bf16)((r < 67) ? Ww1[(size_t)r * 128 + col] : 0.f);
        }
    } else {
        int cc = c - WW2F_OFF; int ct = (cc >> 6) & 3, kc = cc >> 8;
        int col = ct * 16 + l16;
#pragma unroll
        for (int i = 0; i < 8; i++)
            p[i] = (__bf16)Ww2[(size_t)(kc * 32 + row8 + i) * 64 + col];
    }
    wsF[c] = p;
}

// ---------------- world kernel: MFMA, wave-local, barrier-free ----------------
// Wave owns 16 nodes: [16 x 96] @ [96 x 128] relu @ [128 x 64], column-sum
// over valid nodes, 4 atomics/lane (quad 0) into m_agg_w.
__global__ __launch_bounds__(256, 4) void world_kernel(
    const float* __restrict__ z_h, const float* __restrict__ pos_world,
    const bf16x8* __restrict__ Ww1F, const bf16x8* __restrict__ Ww2F,
    const float* __restrict__ bw1, const float* __restrict__ bw2,
    float* __restrict__ m_agg_w)
{
    __shared__ bf16x8 XF[4 * 192];   // 12 KB
    __shared__ bf16x8 HF[4 * 256];   // 16 KB
    const int t = threadIdx.x;
    const int n0 = blockIdx.x * 64;
    const int lane = t & 63, w = t >> 6;
    const int quad = lane >> 4, l16 = lane & 15;

    {   // gather: lane(q=quad, node=l16)
        const int q = quad;
        int node = n0 + w * 16 + l16; if (node >= NN) node = NN - 1;
        const float4* zr = (const float4*)(z_h + (long)node * 64) + q * 4;
        float4 z0 = zr[0], z1 = zr[1], z2 = zr[2], z3 = zr[3];
        bf16x8* Xw = XF + w * 192;
        const int kcs = q >> 1, qa = (q & 1) * 2;
        Xw[kcs * 64 + qa * 16 + l16]       = pack8(z0, z1);
        Xw[kcs * 64 + (qa + 1) * 16 + l16] = pack8(z2, z3);
        bf16x8 f;
#pragma unroll
        for (int i = 0; i < 8; i++) f[i] = (__bf16)0.f;
        if (q == 0) {
            f[0] = (__bf16)(z0.x - pos_world[0]);
            f[1] = (__bf16)(z0.y - pos_world[1]);
            f[2] = (__bf16)(z0.z - pos_world[2]);
        }
        Xw[2 * 64 + q * 16 + l16] = f;
    }

    f32x4 accA[8];
#pragma unroll
    for (int nt = 0; nt < 8; nt++) {
        float b = bw1[nt * 16 + l16];
        f32x4 v = {b, b, b, b}; accA[nt] = v;
    }
#pragma unroll
    for (int kc = 0; kc < 3; kc++) {
        bf16x8 af = XF[w * 192 + kc * 64 + lane];
#pragma unroll
        for (int nt = 0; nt < 8; nt++)
            accA[nt] = __builtin_amdgcn_mfma_f32_16x16x32_bf16(
                af, Ww1F[(kc * 8 + nt) * 64 + lane], accA[nt], 0, 0, 0);
    }
    {   // relu + transpose -> HF (wave-local)
        __bf16* HFp = (__bf16*)(HF + w * 256);
#pragma unroll
        for (int nt = 0; nt < 8; nt++) {
            int kc2 = nt >> 1, qa2 = (nt & 1) * 2 + (l16 >> 3), j = l16 & 7;
#pragma unroll
            for (int r = 0; r < 4; r++)
                HFp[(kc2 * 64 + qa2 * 16 + quad * 4 + r) * 8 + j] =
                    (__bf16)fmaxf(accA[nt][r], 0.f);
        }
    }
    f32x4 acc2[4];
#pragma unroll
    for (int nt = 0; nt < 4; nt++) {
        float b = bw2[nt * 16 + l16];
        f32x4 v = {b, b, b, b}; acc2[nt] = v;
    }
#pragma unroll
    for (int kc = 0; kc < 4; kc++) {
        bf16x8 haf = HF[w * 256 + kc * 64 + lane];
#pragma unroll
        for (int nt = 0; nt < 4; nt++)
            acc2[nt] = __builtin_amdgcn_mfma_f32_16x16x32_bf16(
                haf, Ww2F[(kc * 4 + nt) * 64 + lane], acc2[nt], 0, 0, 0);
    }
    // masked column-sum: in-lane over r, shuffle over quads, atomic from quad 0
#pragma unroll
    for (int nt = 0; nt < 4; nt++) {
        float s = 0.f;
#pragma unroll
        for (int r = 0; r < 4; r++) {
            int node = n0 + w * 16 + quad * 4 + r;
            s += (node < NN) ? acc2[nt][r] : 0.f;
        }
        s += __shfl_xor(s, 16, 64);
        s += __shfl_xor(s, 32, 64);
        if (quad == 0) atomicAdd(m_agg_w + nt * 16 + l16, s);
    }
}

// ---------------- edge kernel: MFMA, wave-local, barrier-free ----------------
// Wave owns 16 edges. Pass A: message hidden (cols 0..127); transpose to HF.
// Pass B: gate hidden (cols 128..255); in-register gate reduce + sigmoid.
// GEMM2 + weighted atomic scatter. Zero __syncthreads.
__global__ __launch_bounds__(256, 4) void edge_kernel(
    const float* __restrict__ z_h, const int* __restrict__ ei,
    const bf16x8* __restrict__ We1F, const bf16x8* __restrict__ We2F,
    const float* __restrict__ be1, const float* __restrict__ be2,
    const float* __restrict__ bg1, const float* __restrict__ Wg2,
    const float* __restrict__ bg2,
    float* __restrict__ m_agg_h)
{
    __shared__ bf16x8 XF[4 * 320];   // 20 KB
    __shared__ bf16x8 HF[4 * 256];   // 16 KB
    __shared__ int tgt_s[64];

    const int t = threadIdx.x;
    const int e0 = blockIdx.x * 64;          // NE % 64 == 0
    const int lane = t & 63, w = t >> 6;
    const int quad = lane >> 4, l16 = lane & 15;

    {   // gather: lane(q=quad, edge=l16)
        const int q = quad;
        const int eg = e0 + w * 16 + l16;
        const int s = ei[eg];
        const int d = ei[NE + eg];
        if (q == 0) tgt_s[w * 16 + l16] = d;
        const float4* zs4 = (const float4*)(z_h + (long)s * 64) + q * 4;
        const float4* zt4 = (const float4*)(z_h + (long)d * 64) + q * 4;
        float4 s0 = zs4[0], s1 = zs4[1], s2 = zs4[2], s3 = zs4[3];
        float4 t0 = zt4[0], t1 = zt4[1], t2 = zt4[2], t3 = zt4[3];
        bf16x8* Xw = XF + w * 320;
        const int kcs = q >> 1, qa = (q & 1) * 2;
        Xw[kcs * 64 + qa * 16 + l16]             = pack8(s0, s1);
        Xw[kcs * 64 + (qa + 1) * 16 + l16]       = pack8(s2, s3);
        Xw[(kcs + 2) * 64 + qa * 16 + l16]       = pack8(t0, t1);
        Xw[(kcs + 2) * 64 + (qa + 1) * 16 + l16] = pack8(t2, t3);
        if (q == 0) {   // edge features -> cols 128..135
            float dx = s0.x - t0.x, dy = s0.y - t0.y, dz = s0.z - t0.z;
            float ax = s0.w, ay = s1.x, az = s1.y;
            float bx = t0.w, by = t1.x, bz = t1.y;
            float cx = ay * bz - az * by;
            float cy = az * bx - ax * bz;
            float cz = ax * by - ay * bx;
            bf16x8 f;
            f[0] = (__bf16)dx; f[1] = (__bf16)dy; f[2] = (__bf16)dz;
            f[3] = (__bf16)(dx * dx + dy * dy + dz * dz);
            f[4] = (__bf16)cx; f[5] = (__bf16)cy; f[6] = (__bf16)cz;
            f[7] = (__bf16)sqrtf(cx * cx + cy * cy + cz * cz);
            Xw[4 * 64 + l16] = f;
        } else {        // zero pad cols 136..159
            bf16x8 z;
#pragma unroll
            for (int i = 0; i < 8; i++) z[i] = (__bf16)0.f;
            Xw[4 * 64 + q * 16 + l16] = z;
        }
    }

    // ---- pass A: message hidden ----
    f32x4 accA[8];
#pragma unroll
    for (int nt = 0; nt < 8; nt++) {
        float b = be1[nt * 16 + l16];
        f32x4 v = {b, b, b, b}; accA[nt] = v;
    }
#pragma unroll
    for (int kc = 0; kc < 5; kc++) {
        bf16x8 af = XF[w * 320 + kc * 64 + lane];
#pragma unroll
        for (int nt = 0; nt < 8; nt++)
            accA[nt] = __builtin_amdgcn_mfma_f32_16x16x32_bf16(
                af, We1F[(kc * 16 + nt) * 64 + lane], accA[nt], 0, 0, 0);
    }
    {   // relu + transpose -> HF (wave-local, same-wave DS ordering)
        __bf16* HFp = (__bf16*)(HF + w * 256);
#pragma unroll
        for (int nt = 0; nt < 8; nt++) {
            int kc2 = nt >> 1, qa2 = (nt & 1) * 2 + (l16 >> 3), j = l16 & 7;
#pragma unroll
            for (int r = 0; r < 4; r++)
                HFp[(kc2 * 64 + qa2 * 16 + quad * 4 + r) * 8 + j] =
                    (__bf16)fmaxf(accA[nt][r], 0.f);
        }
    }

    // ---- pass B: gate hidden ----
    f32x4 accB[8];
#pragma unroll
    for (int nt = 0; nt < 8; nt++) {
        float b = bg1[nt * 16 + l16];
        f32x4 v = {b, b, b, b}; accB[nt] = v;
    }
#pragma unroll
    for (int kc = 0; kc < 5; kc++) {
        bf16x8 af = XF[w * 320 + kc * 64 + lane];
#pragma unroll
        for (int nt = 0; nt < 8; nt++)
            accB[nt] = __builtin_amdgcn_mfma_f32_16x16x32_bf16(
                af, We1F[(kc * 16 + 8 + nt) * 64 + lane], accB[nt], 0, 0, 0);
    }
    float gp[4] = {0.f, 0.f, 0.f, 0.f};
#pragma unroll
    for (int nt = 0; nt < 8; nt++) {
        float wg = Wg2[nt * 16 + l16];
#pragma unroll
        for (int r = 0; r < 4; r++)
            gp[r] += fmaxf(accB[nt][r], 0.f) * wg;
    }
#pragma unroll
    for (int mask = 1; mask < 16; mask <<= 1)
#pragma unroll
        for (int r = 0; r < 4; r++)
            gp[r] += __shfl_xor(gp[r], mask, 64);
    float wgt[4];
    {
        float bg2v = bg2[0];
#pragma unroll
        for (int r = 0; r < 4; r++)
            wgt[r] = 1.f / (1.f + __expf(-(bg2v + gp[r])));
    }

    // ---- GEMM2: message = H @ We2 + be2 ----
    f32x4 acc2[4];
#pragma unroll
    for (int nt = 0; nt < 4; nt++) {
        float b = be2[nt * 16 + l16];
        f32x4 v = {b, b, b, b}; acc2[nt] = v;
    }
#pragma unroll
    for (int kc = 0; kc < 4; kc++) {
        bf16x8 haf = HF[w * 256 + kc * 64 + lane];
#pragma unroll
        for (int nt = 0; nt < 4; nt++)
            acc2[nt] = __builtin_amdgcn_mfma_f32_16x16x32_bf16(
                haf, We2F[(kc * 4 + nt) * 64 + lane], acc2[nt], 0, 0, 0);
    }

    // ---- scatter: w * m -> target rows ----
#pragma unroll
    for (int r = 0; r < 4; r++) {
        int tg = tgt_s[w * 16 + quad * 4 + r];
        float* dst = m_agg_h + (long)tg * 64 + l16;
        float wv = wgt[r];
#pragma unroll
        for (int nt = 0; nt < 4; nt++)
            atomicAdd(dst + nt * 16, acc2[nt][r] * wv);
    }
}

// ---------------- node kernel: MFMA, wave-local, barrier-free ----------------
__global__ __launch_bounds__(256, 4) void node_kernel(
    const float* __restrict__ z_h,
    const float* __restrict__ m_agg_h, const float* __restrict__ m_agg_w,
    const bf16x8* __restrict__ Wn1F, const bf16x8* __restrict__ Wn2F,
    const float* __restrict__ bn1, const float* __restrict__ bn2,
    float* __restrict__ outp)
{
    __shared__ bf16x8 XF[4 * 256];   // 16 KB
    __shared__ bf16x8 HF[4 * 256];   // 16 KB
    const int t = threadIdx.x;
    const int n0 = blockIdx.x * 64;
    const int lane = t & 63, w = t >> 6;
    const int quad = lane >> 4, l16 = lane & 15;

    {   // gather [z | m_agg_h + m_agg_w]
        const int q = quad;
        int node = n0 + w * 16 + l16; if (node >= NN) node = NN - 1;
        const float4* zr = (const float4*)(z_h + (long)node * 64) + q * 4;
        const float4* mr = (const float4*)(m_agg_h + (long)node * 64) + q * 4;
        const float4* mwg = (const float4*)m_agg_w + q * 4;
        float4 z0 = zr[0], z1 = zr[1], z2 = zr[2], z3 = zr[3];
        float4 m0 = mr[0], m1 = mr[1], m2 = mr[2], m3 = mr[3];
        float4 w0 = mwg[0], w1 = mwg[1], w2 = mwg[2], w3 = mwg[3];
        m0.x += w0.x; m0.y += w0.y; m0.z += w0.z; m0.w += w0.w;
        m1.x += w1.x; m1.y += w1.y; m1.z += w1.z; m1.w += w1.w;
        m2.x += w2.x; m2.y += w2.y; m2.z += w2.z; m2.w += w2.w;
        m3.x += w3.x; m3.y += w3.y; m3.z += w3.z; m3.w += w3.w;
        bf16x8* Xw = XF + w * 256;
        const int kcs = q >> 1, qa = (q & 1) * 2;
        Xw[kcs * 64 + qa * 16 + l16]             = pack8(z0, z1);
        Xw[kcs * 64 + (qa + 1) * 16 + l16]       = pack8(z2, z3);
        Xw[(kcs + 2) * 64 + qa * 16 + l16]       = pack8(m0, m1);
        Xw[(kcs + 2) * 64 + (qa + 1) * 16 + l16] = pack8(m2, m3);
    }

    f32x4 accA[8];
#pragma unroll
    for (int nt = 0; nt < 8; nt++) {
        float b = bn1[nt * 16 + l16];
        f32x4 v = {b, b, b, b}; accA[nt] = v;
    }
#pragma unroll
    for (int kc = 0; kc < 4; kc++) {
        bf16x8 af = XF[w * 256 + kc * 64 + lane];
#pragma unroll
        for (int nt = 0; nt < 8; nt++)
            accA[nt] = __builtin_amdgcn_mfma_f32_16x16x32_bf16(
                af, Wn1F[(kc * 8 + nt) * 64 + lane], accA[nt], 0, 0, 0);
    }
    {   // relu + transpose -> HF
        __bf16* HFp = (__bf16*)(HF + w * 256);
#pragma unroll
        for (int nt = 0; nt < 8; nt++) {
            int kc2 = nt >> 1, qa2 = (nt & 1) * 2 + (l16 >> 3), j = l16 & 7;
#pragma unroll
            for (int r = 0; r < 4; r++)
                HFp[(kc2 * 64 + qa2 * 16 + quad * 4 + r) * 8 + j] =
                    (__bf16)fmaxf(accA[nt][r], 0.f);
        }
    }
    f32x4 acc2[4];
#pragma unroll
    for (int nt = 0; nt < 4; nt++) {
        float b = bn2[nt * 16 + l16];
        f32x4 v = {b, b, b, b}; acc2[nt] = v;
    }
#pragma unroll
    for (int kc = 0; kc < 4; kc++) {
        bf16x8 haf = HF[w * 256 + kc * 64 + lane];
#pragma unroll
        for (int nt = 0; nt < 4; nt++)
            acc2[nt] = __builtin_amdgcn_mfma_f32_16x16x32_bf16(
                haf, Wn2F[(kc * 4 + nt) * 64 + lane], acc2[nt], 0, 0, 0);
    }
#pragma unroll
    for (int r = 0; r < 4; r++) {
        int node = n0 + w * 16 + quad * 4 + r;
        if (node < NN) {
            float* dst = outp + (long)node * 64 + l16;
#pragma unroll
            for (int nt = 0; nt < 4; nt++)
                dst[nt * 16] = acc2[nt][r];
        }
    }
}

extern "C" void kernel_launch(void* const* d_in, const int* in_sizes, int n_in,
                              void* d_out, int out_size, void* d_ws, size_t ws_size,
                              hipStream_t stream)
{
    const float* z_h       = (const float*)d_in[0];
    const float* pos_world = (const float*)d_in[1];
    const int*   ei        = (const int*)d_in[2];
    const float* We1 = (const float*)d_in[3];  const float* be1 = (const float*)d_in[4];
    const float* We2 = (const float*)d_in[5];  const float* be2 = (const float*)d_in[6];
    const float* Wg1 = (const float*)d_in[7];  const float* bg1 = (const float*)d_in[8];
    const float* Wg2 = (const float*)d_in[9];  const float* bg2 = (const float*)d_in[10];
    const float* Wn1 = (const float*)d_in[11]; const float* bn1 = (const float*)d_in[12];
    const float* Wn2 = (const float*)d_in[13]; const float* bn2 = (const float*)d_in[14];
    const float* Ww1 = (const float*)d_in[15]; const float* bw1 = (const float*)d_in[16];
    const float* Ww2 = (const float*)d_in[17]; const float* bw2 = (const float*)d_in[18];

    float*  outp    = (float*)d_out;
    float*  m_agg_h = outp;                 // d_out doubles as scatter accumulator
    float*  m_agg_w = (float*)d_ws;         // 64 floats
    bf16x8* wsF     = (bf16x8*)((char*)d_ws + 256);

    hipMemsetAsync(d_out, 0, (size_t)NN * 64 * sizeof(float), stream);
    hipMemsetAsync(d_ws, 0, 256, stream);

    pack_weights<<<(NCHUNKS + 255) / 256, 256, 0, stream>>>(
        We1, Wg1, We2, Wn1, Wn2, Ww1, Ww2, wsF);
    world_kernel<<<(NN + 63) / 64, 256, 0, stream>>>(
        z_h, pos_world, wsF + WW1F_OFF, wsF + WW2F_OFF, bw1, bw2, m_agg_w);
    edge_kernel<<<NE / 64, 256, 0, stream>>>(
        z_h, ei, wsF + WE1F_OFF, wsF + WE2F_OFF,
        be1, be2, bg1, Wg2, bg2, m_agg_h);
    node_kernel<<<(NN + 63) / 64, 256, 0, stream>>>(
        z_h, m_agg_h, m_agg_w, wsF + WN1F_OFF, wsF + WN2F_OFF, bn1, bn2, outp);
}

// Round 6
// 395.848 us; speedup vs baseline: 1.4591x; 1.4591x over previous
//
#include <hip/hip_runtime.h>
#include <math.h>

#define NN 50000
#define NE 800000

typedef float  f32x4  __attribute__((ext_vector_type(4)));
typedef __bf16 bf16x8 __attribute__((ext_vector_type(8)));

// ws layout: [0,256) m_agg_w (64 f32). [256,...) bf16 weight fragments,
// 16B chunks, fragment-linear (chunk = tile*64 + lane):
#define WE1F_OFF 0        // 5120: We1||Wg1  (kc<5, ct<16)  K 136->160
#define WE2F_OFF 5120     // 1024: We2       (kc<4, ct<4)
#define WN1F_OFF 6144     // 2048: Wn1       (kc<4, ct<8)
#define WN2F_OFF 8192     // 1024: Wn2       (kc<4, ct<4)
#define WW1F_OFF 9216     // 1536: Ww1       (kc<3, ct<8)   K 67->96
#define WW2F_OFF 10752    // 1024: Ww2       (kc<4, ct<4)
#define NCHUNKS  11776

__device__ inline bf16x8 pack8(float4 a, float4 b) {
    bf16x8 r;
    r[0] = (__bf16)a.x; r[1] = (__bf16)a.y; r[2] = (__bf16)a.z; r[3] = (__bf16)a.w;
    r[4] = (__bf16)b.x; r[5] = (__bf16)b.y; r[6] = (__bf16)b.z; r[7] = (__bf16)b.w;
    return r;
}

// ---------------- weight fragment pre-pack ----------------
__global__ __launch_bounds__(256) void pack_weights(
    const float* __restrict__ We1, const float* __restrict__ Wg1,
    const float* __restrict__ We2, const float* __restrict__ Wn1,
    const float* __restrict__ Wn2, const float* __restrict__ Ww1,
    const float* __restrict__ Ww2, bf16x8* __restrict__ wsF)
{
    int c = blockIdx.x * 256 + threadIdx.x;
    if (c >= NCHUNKS) return;
    const int lane = c & 63, l16 = lane & 15, row8 = ((lane >> 4) & 3) * 8;
    bf16x8 p;
    if (c < WE2F_OFF) {                       // We1 || Wg1, pad K 136->160
        int ct = (c >> 6) & 15, kc = c >> 10;
        int col = ct * 16 + l16;
        const float* src = (col < 128) ? (We1 + col) : (Wg1 + (col - 128));
#pragma unroll
        for (int i = 0; i < 8; i++) {
            int r = kc * 32 + row8 + i;
            p[i] = (__bf16)((r < 136) ? src[(size_t)r * 128] : 0.f);
        }
    } else if (c < WN1F_OFF) {
        int cc = c - WE2F_OFF; int ct = (cc >> 6) & 3, kc = cc >> 8;
        int col = ct * 16 + l16;
#pragma unroll
        for (int i = 0; i < 8; i++)
            p[i] = (__bf16)We2[(size_t)(kc * 32 + row8 + i) * 64 + col];
    } else if (c < WN2F_OFF) {
        int cc = c - WN1F_OFF; int ct = (cc >> 6) & 7, kc = cc >> 9;
        int col = ct * 16 + l16;
#pragma unroll
        for (int i = 0; i < 8; i++)
            p[i] = (__bf16)Wn1[(size_t)(kc * 32 + row8 + i) * 128 + col];
    } else if (c < WW1F_OFF) {
        int cc = c - WN2F_OFF; int ct = (cc >> 6) & 3, kc = cc >> 8;
        int col = ct * 16 + l16;
#pragma unroll
        for (int i = 0; i < 8; i++)
            p[i] = (__bf16)Wn2[(size_t)(kc * 32 + row8 + i) * 64 + col];
    } else if (c < WW2F_OFF) {                // Ww1, pad K 67->96
        int cc = c - WW1F_OFF; int ct = (cc >> 6) & 7, kc = cc >> 9;
        int col = ct * 16 + l16;
#pragma unroll
        for (int i = 0; i < 8; i++) {
            int r = kc * 32 + row8 + i;
            p[i] = (__bf16)((r < 67) ? Ww1[(size_t)r * 128 + col] : 0.f);
        }
    } else {
        int cc = c - WW2F_OFF; int ct = (cc >> 6) & 3, kc = cc >> 8;
        int col = ct * 16 + l16;
#pragma unroll
        for (int i = 0; i < 8; i++)
            p[i] = (__bf16)Ww2[(size_t)(kc * 32 + row8 + i) * 64 + col];
    }
    wsF[c] = p;
}

// ---------------- world kernel: MFMA, wave-local ----------------
__global__ __launch_bounds__(256, 4) void world_kernel(
    const float* __restrict__ z_h, const float* __restrict__ pos_world,
    const bf16x8* __restrict__ Ww1F, const bf16x8* __restrict__ Ww2F,
    const float* __restrict__ bw1, const float* __restrict__ bw2,
    float* __restrict__ m_agg_w)
{
    __shared__ bf16x8 XF[4 * 192];   // 12 KB
    __shared__ bf16x8 HF[4 * 256];   // 16 KB
    const int t = threadIdx.x;
    const int n0 = blockIdx.x * 64;
    const int lane = t & 63, w = t >> 6;
    const int quad = lane >> 4, l16 = lane & 15;

    {   // gather: lane(q=quad, node=l16)
        const int q = quad;
        int node = n0 + w * 16 + l16; if (node >= NN) node = NN - 1;
        const float4* zr = (const float4*)(z_h + (long)node * 64) + q * 4;
        float4 z0 = zr[0], z1 = zr[1], z2 = zr[2], z3 = zr[3];
        bf16x8* Xw = XF + w * 192;
        const int kcs = q >> 1, qa = (q & 1) * 2;
        Xw[kcs * 64 + qa * 16 + l16]       = pack8(z0, z1);
        Xw[kcs * 64 + (qa + 1) * 16 + l16] = pack8(z2, z3);
        bf16x8 f;
#pragma unroll
        for (int i = 0; i < 8; i++) f[i] = (__bf16)0.f;
        if (q == 0) {
            f[0] = (__bf16)(z0.x - pos_world[0]);
            f[1] = (__bf16)(z0.y - pos_world[1]);
            f[2] = (__bf16)(z0.z - pos_world[2]);
        }
        Xw[2 * 64 + q * 16 + l16] = f;
    }

    f32x4 accA[8];
#pragma unroll
    for (int nt = 0; nt < 8; nt++) {
        float b = bw1[nt * 16 + l16];
        f32x4 v = {b, b, b, b}; accA[nt] = v;
    }
#pragma unroll
    for (int kc = 0; kc < 3; kc++) {
        bf16x8 af = XF[w * 192 + kc * 64 + lane];
#pragma unroll
        for (int nt = 0; nt < 8; nt++)
            accA[nt] = __builtin_amdgcn_mfma_f32_16x16x32_bf16(
                af, Ww1F[(kc * 8 + nt) * 64 + lane], accA[nt], 0, 0, 0);
    }
    {   // relu + transpose -> HF (wave-local)
        __bf16* HFp = (__bf16*)(HF + w * 256);
#pragma unroll
        for (int nt = 0; nt < 8; nt++) {
            int kc2 = nt >> 1, qa2 = (nt & 1) * 2 + (l16 >> 3), j = l16 & 7;
#pragma unroll
            for (int r = 0; r < 4; r++)
                HFp[(kc2 * 64 + qa2 * 16 + quad * 4 + r) * 8 + j] =
                    (__bf16)fmaxf(accA[nt][r], 0.f);
        }
    }
    f32x4 acc2[4];
#pragma unroll
    for (int nt = 0; nt < 4; nt++) {
        float b = bw2[nt * 16 + l16];
        f32x4 v = {b, b, b, b}; acc2[nt] = v;
    }
#pragma unroll
    for (int kc = 0; kc < 4; kc++) {
        bf16x8 haf = HF[w * 256 + kc * 64 + lane];
#pragma unroll
        for (int nt = 0; nt < 4; nt++)
            acc2[nt] = __builtin_amdgcn_mfma_f32_16x16x32_bf16(
                haf, Ww2F[(kc * 4 + nt) * 64 + lane], acc2[nt], 0, 0, 0);
    }
#pragma unroll
    for (int nt = 0; nt < 4; nt++) {
        float s = 0.f;
#pragma unroll
        for (int r = 0; r < 4; r++) {
            int node = n0 + w * 16 + quad * 4 + r;
            s += (node < NN) ? acc2[nt][r] : 0.f;
        }
        s += __shfl_xor(s, 16, 64);
        s += __shfl_xor(s, 32, 64);
        if (quad == 0) atomicAdd(m_agg_w + nt * 16 + l16, s);
    }
}

// ---------------- edge kernel: 8 waves, N-shared, XF/HF union ----------------
// 64 edges/block, 512 threads. Wave w owns GEMM1 col-tiles {2w, 2w+1}:
// waves 0-3 = message cols (0..127), waves 4-7 = gate cols (128..255).
// Weight fragments read from L2 exactly once per block. XF and HF share LDS
// (HF written only after all XF reads, barrier-guarded).
union EdgeU { bf16x8 XF[1280]; bf16x8 HF[1024]; };   // 20 KB

__global__ __launch_bounds__(512, 6) void edge_kernel(
    const float* __restrict__ z_h, const int* __restrict__ ei,
    const bf16x8* __restrict__ We1F, const bf16x8* __restrict__ We2F,
    const float* __restrict__ be1, const float* __restrict__ be2,
    const float* __restrict__ bg1, const float* __restrict__ Wg2,
    const float* __restrict__ bg2,
    float* __restrict__ m_agg_h)
{
    __shared__ EdgeU U;
    __shared__ int   tgt_s[64];
    __shared__ float gred[4][64];
    __shared__ float wgt[64];

    const int t = threadIdx.x;               // 0..511
    const int e0 = blockIdx.x * 64;          // NE % 64 == 0
    const int lane = t & 63, w = t >> 6;     // w 0..7
    const int quad = lane >> 4, l16 = lane & 15;

    {   // ---- gather: 8 threads/edge (side 0 = src, side 1 = tgt) ----
        const int ee = t >> 3, q = t & 7;
        const int side = q >> 2, sub = q & 3;
        const int mt = ee >> 4, l16e = ee & 15;
        const int eg = e0 + ee;
        const int row = side ? ei[NE + eg] : ei[eg];
        if (q == 4) tgt_s[ee] = row;
        const float4* zr = (const float4*)(z_h + (long)row * 64) + sub * 4;
        float4 a0 = zr[0], a1 = zr[1], a2 = zr[2], a3 = zr[3];
        const int kcs = (sub >> 1) + side * 2, qa = (sub & 1) * 2;
        U.XF[(kcs * 4 + mt) * 64 + qa * 16 + l16e]       = pack8(a0, a1);
        U.XF[(kcs * 4 + mt) * 64 + (qa + 1) * 16 + l16e] = pack8(a2, a3);
        if (q == 0) {       // edge features (cols 128..135)
            const float4* zt = (const float4*)(z_h + (long)ei[NE + eg] * 64);
            float4 t0 = zt[0], t1 = zt[1];
            float dx = a0.x - t0.x, dy = a0.y - t0.y, dz = a0.z - t0.z;
            float ax = a0.w, ay = a1.x, az = a1.y;
            float bx = t0.w, by = t1.x, bz = t1.y;
            float cx = ay * bz - az * by;
            float cy = az * bx - ax * bz;
            float cz = ax * by - ay * bx;
            bf16x8 f;
            f[0] = (__bf16)dx; f[1] = (__bf16)dy; f[2] = (__bf16)dz;
            f[3] = (__bf16)(dx * dx + dy * dy + dz * dz);
            f[4] = (__bf16)cx; f[5] = (__bf16)cy; f[6] = (__bf16)cz;
            f[7] = (__bf16)sqrtf(cx * cx + cy * cy + cz * cz);
            U.XF[(16 + mt) * 64 + l16e] = f;
        } else if (q >= 5) { // zero pad (cols 136..159)
            bf16x8 z;
#pragma unroll
            for (int i = 0; i < 8; i++) z[i] = (__bf16)0.f;
            U.XF[(16 + mt) * 64 + (q - 4) * 16 + l16e] = z;
        }
    }
    __syncthreads();                         // B1: XF ready

    // ---- GEMM1: wave owns 32 cols (tiles 2w, 2w+1) ----
    f32x4 acc[4][2];
#pragma unroll
    for (int nt = 0; nt < 2; nt++) {
        int col = (w * 2 + nt) * 16 + l16;
        float b = (col < 128) ? be1[col] : bg1[col - 128];
#pragma unroll
        for (int mt = 0; mt < 4; mt++) { f32x4 v = {b, b, b, b}; acc[mt][nt] = v; }
    }
#pragma unroll
    for (int kc = 0; kc < 5; kc++) {
        bf16x8 af[4], bfr[2];
#pragma unroll
        for (int mt = 0; mt < 4; mt++) af[mt] = U.XF[(kc * 4 + mt) * 64 + lane];
#pragma unroll
        for (int nt = 0; nt < 2; nt++)
            bfr[nt] = We1F[(kc * 16 + w * 2 + nt) * 64 + lane];
#pragma unroll
        for (int mt = 0; mt < 4; mt++)
#pragma unroll
            for (int nt = 0; nt < 2; nt++)
                acc[mt][nt] = __builtin_amdgcn_mfma_f32_16x16x32_bf16(
                    af[mt], bfr[nt], acc[mt][nt], 0, 0, 0);
    }
    __syncthreads();                         // B2: all XF reads done (HF may overwrite)

    if (w < 4) {
        // ---- message waves: relu + transpose into HF (GEMM2-A order) ----
        __bf16* HFp = (__bf16*)U.HF;
#pragma unroll
        for (int nt = 0; nt < 2; nt++) {
            int cw = (w * 2 + nt) * 16 + l16;
            int kc2 = cw >> 5, quad2 = (cw >> 3) & 3, ii = cw & 7;
#pragma unroll
            for (int mt = 0; mt < 4; mt++)
#pragma unroll
                for (int r = 0; r < 4; r++)
                    HFp[(((kc2 * 4 + mt) * 64) + quad2 * 16 + quad * 4 + r) * 8 + ii] =
                        (__bf16)fmaxf(acc[mt][nt][r], 0.f);
        }
    } else {
        // ---- gate waves: in-register partials over their 32 gate cols ----
        float gp[4][4];
#pragma unroll
        for (int mt = 0; mt < 4; mt++)
#pragma unroll
            for (int r = 0; r < 4; r++) gp[mt][r] = 0.f;
#pragma unroll
        for (int nt = 0; nt < 2; nt++) {
            float wg = Wg2[((w - 4) * 2 + nt) * 16 + l16];
#pragma unroll
            for (int mt = 0; mt < 4; mt++)
#pragma unroll
                for (int r = 0; r < 4; r++)
                    gp[mt][r] += fmaxf(acc[mt][nt][r], 0.f) * wg;
        }
#pragma unroll
        for (int mask = 1; mask < 16; mask <<= 1)
#pragma unroll
            for (int mt = 0; mt < 4; mt++)
#pragma unroll
                for (int r = 0; r < 4; r++)
                    gp[mt][r] += __shfl_xor(gp[mt][r], mask, 64);
        if (l16 == 0) {
#pragma unroll
            for (int mt = 0; mt < 4; mt++)
#pragma unroll
                for (int r = 0; r < 4; r++)
                    gred[w - 4][mt * 16 + quad * 4 + r] = gp[mt][r];
        }
    }
    __syncthreads();                         // B3: HF + gred ready

    if (t < 64) {                            // 64 sigmoids per block
        float g = bg2[0] + gred[0][t] + gred[1][t] + gred[2][t] + gred[3][t];
        wgt[t] = 1.f / (1.f + __expf(-g));
    }

    // ---- GEMM2 (waves 0-3): message = H @ We2 + be2 ----
    f32x4 acc2[4];
    if (w < 4) {
        float b2 = be2[w * 16 + l16];
#pragma unroll
        for (int mt = 0; mt < 4; mt++) { f32x4 v = {b2, b2, b2, b2}; acc2[mt] = v; }
#pragma unroll
        for (int kc = 0; kc < 4; kc++) {
            bf16x8 b2f = We2F[(kc * 4 + w) * 64 + lane];
#pragma unroll
            for (int mt = 0; mt < 4; mt++)
                acc2[mt] = __builtin_amdgcn_mfma_f32_16x16x32_bf16(
                    U.HF[(kc * 4 + mt) * 64 + lane], b2f, acc2[mt], 0, 0, 0);
        }
    }
    __syncthreads();                         // B4: wgt ready

    if (w < 4) {
        // ---- scatter: w * m -> target rows ----
#pragma unroll
        for (int mt = 0; mt < 4; mt++)
#pragma unroll
            for (int r = 0; r < 4; r++) {
                int edge = mt * 16 + quad * 4 + r;
                atomicAdd(m_agg_h + (long)tgt_s[edge] * 64 + w * 16 + l16,
                          acc2[mt][r] * wgt[edge]);
            }
    }
}

// ---------------- node kernel: MFMA, wave-local ----------------
__global__ __launch_bounds__(256, 4) void node_kernel(
    const float* __restrict__ z_h,
    const float* __restrict__ m_agg_h, const float* __restrict__ m_agg_w,
    const bf16x8* __restrict__ Wn1F, const bf16x8* __restrict__ Wn2F,
    const float* __restrict__ bn1, const float* __restrict__ bn2,
    float* __restrict__ outp)
{
    __shared__ bf16x8 XF[4 * 256];   // 16 KB
    __shared__ bf16x8 HF[4 * 256];   // 16 KB
    const int t = threadIdx.x;
    const int n0 = blockIdx.x * 64;
    const int lane = t & 63, w = t >> 6;
    const int quad = lane >> 4, l16 = lane & 15;

    {   // gather [z | m_agg_h + m_agg_w]
        const int q = quad;
        int node = n0 + w * 16 + l16; if (node >= NN) node = NN - 1;
        const float4* zr = (const float4*)(z_h + (long)node * 64) + q * 4;
        const float4* mr = (const float4*)(m_agg_h + (long)node * 64) + q * 4;
        const float4* mwg = (const float4*)m_agg_w + q * 4;
        float4 z0 = zr[0], z1 = zr[1], z2 = zr[2], z3 = zr[3];
        float4 m0 = mr[0], m1 = mr[1], m2 = mr[2], m3 = mr[3];
        float4 w0 = mwg[0], w1 = mwg[1], w2 = mwg[2], w3 = mwg[3];
        m0.x += w0.x; m0.y += w0.y; m0.z += w0.z; m0.w += w0.w;
        m1.x += w1.x; m1.y += w1.y; m1.z += w1.z; m1.w += w1.w;
        m2.x += w2.x; m2.y += w2.y; m2.z += w2.z; m2.w += w2.w;
        m3.x += w3.x; m3.y += w3.y; m3.z += w3.z; m3.w += w3.w;
        bf16x8* Xw = XF + w * 256;
        const int kcs = q >> 1, qa = (q & 1) * 2;
        Xw[kcs * 64 + qa * 16 + l16]             = pack8(z0, z1);
        Xw[kcs * 64 + (qa + 1) * 16 + l16]       = pack8(z2, z3);
        Xw[(kcs + 2) * 64 + qa * 16 + l16]       = pack8(m0, m1);
        Xw[(kcs + 2) * 64 + (qa + 1) * 16 + l16] = pack8(m2, m3);
    }

    f32x4 accA[8];
#pragma unroll
    for (int nt = 0; nt < 8; nt++) {
        float b = bn1[nt * 16 + l16];
        f32x4 v = {b, b, b, b}; accA[nt] = v;
    }
#pragma unroll
    for (int kc = 0; kc < 4; kc++) {
        bf16x8 af = XF[w * 256 + kc * 64 + lane];
#pragma unroll
        for (int nt = 0; nt < 8; nt++)
            accA[nt] = __builtin_amdgcn_mfma_f32_16x16x32_bf16(
                af, Wn1F[(kc * 8 + nt) * 64 + lane], accA[nt], 0, 0, 0);
    }
    {   // relu + transpose -> HF
        __bf16* HFp = (__bf16*)(HF + w * 256);
#pragma unroll
        for (int nt = 0; nt < 8; nt++) {
            int kc2 = nt >> 1, qa2 = (nt & 1) * 2 + (l16 >> 3), j = l16 & 7;
#pragma unroll
            for (int r = 0; r < 4; r++)
                HFp[(kc2 * 64 + qa2 * 16 + quad * 4 + r) * 8 + j] =
                    (__bf16)fmaxf(accA[nt][r], 0.f);
        }
    }
    f32x4 acc2[4];
#pragma unroll
    for (int nt = 0; nt < 4; nt++) {
        float b = bn2[nt * 16 + l16];
        f32x4 v = {b, b, b, b}; acc2[nt] = v;
    }
#pragma unroll
    for (int kc = 0; kc < 4; kc++) {
        bf16x8 haf = HF[w * 256 + kc * 64 + lane];
#pragma unroll
        for (int nt = 0; nt < 4; nt++)
            acc2[nt] = __builtin_amdgcn_mfma_f32_16x16x32_bf16(
                haf, Wn2F[(kc * 4 + nt) * 64 + lane], acc2[nt], 0, 0, 0);
    }
#pragma unroll
    for (int r = 0; r < 4; r++) {
        int node = n0 + w * 16 + quad * 4 + r;
        if (node < NN) {
            float* dst = outp + (long)node * 64 + l16;
#pragma unroll
            for (int nt = 0; nt < 4; nt++)
                dst[nt * 16] = acc2[nt][r];
        }
    }
}

extern "C" void kernel_launch(void* const* d_in, const int* in_sizes, int n_in,
                              void* d_out, int out_size, void* d_ws, size_t ws_size,
                              hipStream_t stream)
{
    const float* z_h       = (const float*)d_in[0];
    const float* pos_world = (const float*)d_in[1];
    const int*   ei        = (const int*)d_in[2];
    const float* We1 = (const float*)d_in[3];  const float* be1 = (const float*)d_in[4];
    const float* We2 = (const float*)d_in[5];  const float* be2 = (const float*)d_in[6];
    const float* Wg1 = (const float*)d_in[7];  const float* bg1 = (const float*)d_in[8];
    const float* Wg2 = (const float*)d_in[9];  const float* bg2 = (const float*)d_in[10];
    const float* Wn1 = (const float*)d_in[11]; const float* bn1 = (const float*)d_in[12];
    const float* Wn2 = (const float*)d_in[13]; const float* bn2 = (const float*)d_in[14];
    const float* Ww1 = (const float*)d_in[15]; const float* bw1 = (const float*)d_in[16];
    const float* Ww2 = (const float*)d_in[17]; const float* bw2 = (const float*)d_in[18];

    float*  outp    = (float*)d_out;
    float*  m_agg_h = outp;                 // d_out doubles as scatter accumulator
    float*  m_agg_w = (float*)d_ws;         // 64 floats
    bf16x8* wsF     = (bf16x8*)((char*)d_ws + 256);

    hipMemsetAsync(d_out, 0, (size_t)NN * 64 * sizeof(float), stream);
    hipMemsetAsync(d_ws, 0, 256, stream);

    pack_weights<<<(NCHUNKS + 255) / 256, 256, 0, stream>>>(
        We1, Wg1, We2, Wn1, Wn2, Ww1, Ww2, wsF);
    world_kernel<<<(NN + 63) / 64, 256, 0, stream>>>(
        z_h, pos_world, wsF + WW1F_OFF, wsF + WW2F_OFF, bw1, bw2, m_agg_w);
    edge_kernel<<<NE / 64, 512, 0, stream>>>(
        z_h, ei, wsF + WE1F_OFF, wsF + WE2F_OFF,
        be1, be2, bg1, Wg2, bg2, m_agg_h);
    node_kernel<<<(NN + 63) / 64, 256, 0, stream>>>(
        z_h, m_agg_h, m_agg_w, wsF + WN1F_OFF, wsF + WN2F_OFF, bn1, bn2, outp);
}